// Round 2
// baseline (614.331 us; speedup 1.0000x reference)
//
#include <hip/hip_runtime.h>
#include <math.h>

// MoE router: logits -> top-2 -> softmax -> capacity-ranked dispatch.
// Output layout (all float32, concatenated):
//   used_capacity[E], cb_weight[N*E*C], sec_mask[N*E*C].
//
// Structure:
//   K1 logits_topk:  per-token logits + top-2 + 2-way softmax -> slot arrays
//   K2 rank_kernel:  single block, exact sequential ranks via ballot prefix
//                    -> compact table rank[n*E+e], val[n*E+e]; used_capacity
//   K3 write_out:    single streaming pass writes ALL of cb_weight+sec_mask
//                    (float4, every byte written exactly once; no memset)

#define HDIM 1024
#define NEXP 8

__global__ __launch_bounds__(256) void logits_topk_kernel(
    const float* __restrict__ x, const float* __restrict__ wg,
    int* __restrict__ expert_slot, float* __restrict__ prob_slot, int N) {
  __shared__ float w_lds[NEXP * HDIM];  // 32 KB
  const int tid = threadIdx.x;
  for (int i = tid; i < NEXP * HDIM; i += blockDim.x) w_lds[i] = wg[i];
  __syncthreads();

  const int wave = tid >> 6;
  const int lane = tid & 63;
  const int n = blockIdx.x * 4 + wave;
  if (n >= N) return;

  const float* xr = x + (size_t)n * HDIM;
  float acc[NEXP];
#pragma unroll
  for (int e = 0; e < NEXP; e++) acc[e] = 0.0f;

  for (int j = 0; j < HDIM; j += 64) {
    float xv = xr[j + lane];
#pragma unroll
    for (int e = 0; e < NEXP; e++) acc[e] += xv * w_lds[e * HDIM + j + lane];
  }

#pragma unroll
  for (int e = 0; e < NEXP; e++) {
    float v = acc[e];
    for (int off = 32; off > 0; off >>= 1) v += __shfl_down(v, off, 64);
    acc[e] = v;
  }

  if (lane == 0) {
    // top-2, ties -> lower index (matches lax.top_k)
    int b0 = 0;
    float v0 = acc[0];
#pragma unroll
    for (int e = 1; e < NEXP; e++) {
      if (acc[e] > v0) { v0 = acc[e]; b0 = e; }
    }
    int b1 = -1;
    float v1 = -INFINITY;
#pragma unroll
    for (int e = 0; e < NEXP; e++) {
      if (e == b0) continue;
      if (acc[e] > v1) { v1 = acc[e]; b1 = e; }
    }
    float e2 = expf(v1 - v0);
    float p0 = 1.0f / (1.0f + e2);
    float p1 = e2 / (1.0f + e2);
    expert_slot[n] = b0;
    expert_slot[N + n] = b1;
    prob_slot[n] = p0;
    prob_slot[N + n] = p1;
  }
}

// One block, 8 waves; wave w owns expert w. Exact sequential ranks over
// slot order s = k*N + n via ballot prefix counting. Writes compact table.
__global__ __launch_bounds__(512) void rank_kernel(
    const int* __restrict__ expert_slot, const float* __restrict__ prob_slot,
    float* __restrict__ used_cap, int* __restrict__ rank_t,
    float* __restrict__ val_t, int N, int C) {
  const int tid = threadIdx.x;
  // init rank table to -1 (ws is poisoned)
  for (int i = tid; i < N * NEXP; i += 512) rank_t[i] = -1;
  __syncthreads();

  const int w = tid >> 6;  // expert id, 0..7
  const int lane = tid & 63;
  const int S = 2 * N;
  const unsigned long long below_mask = (lane == 63) ? 0x7FFFFFFFFFFFFFFFull
                                                     : ((1ull << lane) - 1ull);
  int prefix = 0;
  for (int base = 0; base < S; base += 256) {
    int s0 = base + lane;
    int s1 = base + 64 + lane;
    int s2 = base + 128 + lane;
    int s3 = base + 192 + lane;
    int e0 = expert_slot[s0];
    int e1 = expert_slot[s1];
    int e2 = expert_slot[s2];
    int e3 = expert_slot[s3];
#pragma unroll
    for (int u = 0; u < 4; u++) {
      int s = (u == 0) ? s0 : (u == 1) ? s1 : (u == 2) ? s2 : s3;
      int e = (u == 0) ? e0 : (u == 1) ? e1 : (u == 2) ? e2 : e3;
      bool match = (e == w);
      unsigned long long m = __ballot(match);
      int rank = prefix + __popcll(m & below_mask);
      if (match && rank < C) {
        int n = (s >= N) ? (s - N) : s;
        rank_t[n * NEXP + w] = rank;
        val_t[n * NEXP + w] = prob_slot[s];
      }
      prefix += __popcll(m);
    }
  }
  if (lane == 0) used_cap[w] = (float)(prefix < C ? prefix : C);
}

// Streaming writer: one float4 of cb + one float4 of sec per thread.
// total4 = N*E*C/4; row = t / (C/4); c4 = t % (C/4).
__global__ __launch_bounds__(256) void write_out_kernel(
    const int* __restrict__ rank_t, const float* __restrict__ val_t,
    float* __restrict__ cb, float* __restrict__ sec, int C4, int total4) {
  int t = blockIdx.x * 256 + threadIdx.x;
  if (t >= total4) return;
  int row = t / C4;        // n*NEXP + e  (C4=512 -> magic-mul)
  int c4 = t - row * C4;
  int rk = rank_t[row];    // broadcast within wave (same row for 8 waves/row)
  float4 v = {0.0f, 0.0f, 0.0f, 0.0f};
  float4 s = {0.0f, 0.0f, 0.0f, 0.0f};
  if ((rk >> 2) == c4) {   // rk == -1 -> (rk>>2) == -1, never matches
    float val = val_t[row];
    ((float*)&v)[rk & 3] = val;
    ((float*)&s)[rk & 3] = (val != 0.0f) ? 1.0f : 0.0f;
  }
  ((float4*)cb)[t] = v;
  ((float4*)sec)[t] = s;
}

extern "C" void kernel_launch(void* const* d_in, const int* in_sizes, int n_in,
                              void* d_out, int out_size, void* d_ws, size_t ws_size,
                              hipStream_t stream) {
  const float* x = (const float*)d_in[0];
  const float* wg = (const float*)d_in[1];

  const int N = in_sizes[0] / HDIM;  // 4096 tokens
  const int K = 2;
  int capacity = (int)floor((double)K * 2.0 * (double)N / (double)NEXP);
  if (capacity < 4) capacity = 4;

  float* out = (float*)d_out;
  float* used_cap = out;
  float* cb = out + NEXP;
  float* sec = cb + (size_t)N * NEXP * (size_t)capacity;

  char* ws = (char*)d_ws;
  int* expert_slot = (int*)ws;                               // 2N ints
  float* prob_slot = (float*)(ws + 4 * (size_t)(2 * N));     // 2N floats
  int* rank_t = (int*)(ws + 8 * (size_t)(2 * N));            // N*E ints
  float* val_t = (float*)(ws + 8 * (size_t)(2 * N) + 4 * (size_t)(N * NEXP));

  logits_topk_kernel<<<(N + 3) / 4, 256, 0, stream>>>(x, wg, expert_slot,
                                                      prob_slot, N);
  rank_kernel<<<1, 512, 0, stream>>>(expert_slot, prob_slot, used_cap, rank_t,
                                     val_t, N, capacity);
  int C4 = capacity / 4;
  int total4 = N * NEXP * C4;
  write_out_kernel<<<(total4 + 255) / 256, 256, 0, stream>>>(rank_t, val_t, cb,
                                                             sec, C4, total4);
}

// Round 3
// 581.455 us; speedup vs baseline: 1.0565x; 1.0565x over previous
//
#include <hip/hip_runtime.h>
#include <math.h>

// MoE router: logits -> top-2 -> softmax -> capacity-ranked dispatch.
// Output layout (all float32, concatenated):
//   used_capacity[E], cb_weight[N*E*C], sec_mask[N*E*C].
//
// R3 structure (memset at fill-rate + compact scatter):
//   M  hipMemsetAsync: zero all 537 MB of d_out at the fast fill path (~87us)
//   K1 logits_topk:    per-token logits + top-2 + 2-way softmax -> slot arrays
//   K2 rank_kernel:    single block, exact sequential ranks via ballot prefix
//                      -> compact per-expert lists (offset,value) + counts
//   K3 scatter_kernel: 16K threads write the 8192x2 nonzeros + used_capacity

#define HDIM 1024
#define NEXP 8

__global__ __launch_bounds__(256) void logits_topk_kernel(
    const float* __restrict__ x, const float* __restrict__ wg,
    int* __restrict__ expert_slot, float* __restrict__ prob_slot, int N) {
  __shared__ float w_lds[NEXP * HDIM];  // 32 KB
  const int tid = threadIdx.x;
  for (int i = tid; i < NEXP * HDIM; i += blockDim.x) w_lds[i] = wg[i];
  __syncthreads();

  const int wave = tid >> 6;
  const int lane = tid & 63;
  const int n = blockIdx.x * 4 + wave;
  if (n >= N) return;

  const float* xr = x + (size_t)n * HDIM;
  float acc[NEXP];
#pragma unroll
  for (int e = 0; e < NEXP; e++) acc[e] = 0.0f;

  for (int j = 0; j < HDIM; j += 64) {
    float xv = xr[j + lane];
#pragma unroll
    for (int e = 0; e < NEXP; e++) acc[e] += xv * w_lds[e * HDIM + j + lane];
  }

#pragma unroll
  for (int e = 0; e < NEXP; e++) {
    float v = acc[e];
    for (int off = 32; off > 0; off >>= 1) v += __shfl_down(v, off, 64);
    acc[e] = v;
  }

  if (lane == 0) {
    // top-2, ties -> lower index (matches lax.top_k)
    int b0 = 0;
    float v0 = acc[0];
#pragma unroll
    for (int e = 1; e < NEXP; e++) {
      if (acc[e] > v0) { v0 = acc[e]; b0 = e; }
    }
    int b1 = -1;
    float v1 = -INFINITY;
#pragma unroll
    for (int e = 0; e < NEXP; e++) {
      if (e == b0) continue;
      if (acc[e] > v1) { v1 = acc[e]; b1 = e; }
    }
    float e2 = expf(v1 - v0);
    float p0 = 1.0f / (1.0f + e2);
    float p1 = e2 / (1.0f + e2);
    expert_slot[n] = b0;
    expert_slot[N + n] = b1;
    prob_slot[n] = p0;
    prob_slot[N + n] = p1;
  }
}

// One block, 8 waves; wave w owns expert w. Exact sequential ranks over
// slot order s = k*N + n via ballot prefix counting. Emits compact lists:
// offs/vals[w*C + rank] for rank < C, and raw count cnt[w].
__global__ __launch_bounds__(512) void rank_kernel(
    const int* __restrict__ expert_slot, const float* __restrict__ prob_slot,
    int* __restrict__ cnt, int* __restrict__ offs, float* __restrict__ vals,
    int N, int C) {
  const int w = threadIdx.x >> 6;  // expert id, 0..7
  const int lane = threadIdx.x & 63;
  const int S = 2 * N;
  const unsigned long long below_mask = (lane == 63) ? 0x7FFFFFFFFFFFFFFFull
                                                     : ((1ull << lane) - 1ull);
  int prefix = 0;
  for (int base = 0; base < S; base += 256) {
    int s0 = base + lane;
    int s1 = base + 64 + lane;
    int s2 = base + 128 + lane;
    int s3 = base + 192 + lane;
    int e0 = expert_slot[s0];
    int e1 = expert_slot[s1];
    int e2 = expert_slot[s2];
    int e3 = expert_slot[s3];
#pragma unroll
    for (int u = 0; u < 4; u++) {
      int s = (u == 0) ? s0 : (u == 1) ? s1 : (u == 2) ? s2 : s3;
      int e = (u == 0) ? e0 : (u == 1) ? e1 : (u == 2) ? e2 : e3;
      bool match = (e == w);
      unsigned long long m = __ballot(match);
      int rank = prefix + __popcll(m & below_mask);
      if (match && rank < C) {
        int n = (s >= N) ? (s - N) : s;
        offs[w * C + rank] = (n * NEXP + w) * C + rank;
        vals[w * C + rank] = prob_slot[s];
      }
      prefix += __popcll(m);
    }
  }
  if (lane == 0) cnt[w] = prefix;
}

// NEXP*C threads: thread i -> expert w = i/C, list index j = i%C.
__global__ __launch_bounds__(256) void scatter_kernel(
    const int* __restrict__ cnt, const int* __restrict__ offs,
    const float* __restrict__ vals, float* __restrict__ used_cap,
    float* __restrict__ cb, float* __restrict__ sec, int C) {
  int i = blockIdx.x * 256 + threadIdx.x;
  int w = i / C;
  if (w >= NEXP) return;
  int j = i - w * C;
  int c = cnt[w];
  int cc = (c < C) ? c : C;
  if (j < cc) {
    int o = offs[i];
    cb[o] = vals[i];
    sec[o] = 1.0f;
  }
  if (j == 0) used_cap[w] = (float)cc;
}

extern "C" void kernel_launch(void* const* d_in, const int* in_sizes, int n_in,
                              void* d_out, int out_size, void* d_ws, size_t ws_size,
                              hipStream_t stream) {
  const float* x = (const float*)d_in[0];
  const float* wg = (const float*)d_in[1];

  const int N = in_sizes[0] / HDIM;  // 4096 tokens
  const int K = 2;
  int capacity = (int)floor((double)K * 2.0 * (double)N / (double)NEXP);
  if (capacity < 4) capacity = 4;

  float* out = (float*)d_out;
  float* used_cap = out;
  float* cb = out + NEXP;
  float* sec = cb + (size_t)N * NEXP * (size_t)capacity;

  char* ws = (char*)d_ws;
  int* expert_slot = (int*)ws;                                  // 2N ints
  float* prob_slot = (float*)(ws + 4 * (size_t)(2 * N));        // 2N floats
  int* cnt = (int*)(ws + 8 * (size_t)(2 * N));                  // NEXP ints
  int* offs = (int*)(ws + 8 * (size_t)(2 * N) + 4 * NEXP);      // NEXP*C ints
  float* vals = (float*)(ws + 8 * (size_t)(2 * N) + 4 * NEXP +
                         4 * (size_t)(NEXP * capacity));        // NEXP*C floats

  // Zero the (poisoned) 537 MB output via the fast fill path (~6.1 TB/s).
  hipMemsetAsync(d_out, 0, sizeof(float) * (size_t)out_size, stream);

  logits_topk_kernel<<<(N + 3) / 4, 256, 0, stream>>>(x, wg, expert_slot,
                                                      prob_slot, N);
  rank_kernel<<<1, 512, 0, stream>>>(expert_slot, prob_slot, cnt, offs, vals,
                                     N, capacity);
  int total = NEXP * capacity;
  scatter_kernel<<<(total + 255) / 256, 256, 0, stream>>>(cnt, offs, vals,
                                                          used_cap, cb, sec,
                                                          capacity);
}

// Round 4
// 534.567 us; speedup vs baseline: 1.1492x; 1.0877x over previous
//
#include <hip/hip_runtime.h>
#include <math.h>

// MoE router: logits -> top-2 -> softmax -> capacity-ranked dispatch.
// Output layout (all float32, concatenated):
//   used_capacity[E], cb_weight[N*E*C], sec_mask[N*E*C].
//
// R4 structure (fully parallel rank pipeline):
//   M  hipMemsetAsync: zero 537 MB of d_out at fill-rate (~87us, unavoidable)
//   K1 logits_topk:  per-token logits + top-2 + 2-way softmax (float4 loads)
//   K2 count:        per-64-slot-chunk per-expert counts via ballot (parallel)
//   K3 scan:         exclusive scan of chunk counts per expert (8 waves, shfl)
//   K4 scatter:      wave per chunk: intra-chunk rank via ballot + chunk base,
//                    write the ~8192x2 nonzeros; used_capacity from K3.

#define HDIM 1024
#define NEXP 8

__global__ __launch_bounds__(256) void logits_topk_kernel(
    const float* __restrict__ x, const float* __restrict__ wg,
    int* __restrict__ expert_slot, float* __restrict__ prob_slot, int N) {
  __shared__ float w_lds[NEXP * HDIM];  // 32 KB
  const int tid = threadIdx.x;
  for (int i = tid; i < NEXP * HDIM / 4; i += blockDim.x)
    ((float4*)w_lds)[i] = ((const float4*)wg)[i];
  __syncthreads();

  const int wave = tid >> 6;
  const int lane = tid & 63;
  const int n = blockIdx.x * 4 + wave;
  if (n >= N) return;

  const float* xr = x + (size_t)n * HDIM;
  float acc[NEXP];
#pragma unroll
  for (int e = 0; e < NEXP; e++) acc[e] = 0.0f;

  // lane reads float4 at j + lane*4; 4 iterations cover HDIM=1024.
#pragma unroll
  for (int j = 0; j < HDIM; j += 256) {
    float4 xv = ((const float4*)(xr + j))[lane];
#pragma unroll
    for (int e = 0; e < NEXP; e++) {
      float4 wv = ((const float4*)(w_lds + e * HDIM + j))[lane];
      acc[e] += xv.x * wv.x + xv.y * wv.y + xv.z * wv.z + xv.w * wv.w;
    }
  }

#pragma unroll
  for (int e = 0; e < NEXP; e++) {
    float v = acc[e];
    for (int off = 32; off > 0; off >>= 1) v += __shfl_down(v, off, 64);
    acc[e] = v;
  }

  if (lane == 0) {
    // top-2, ties -> lower index (matches lax.top_k)
    int b0 = 0;
    float v0 = acc[0];
#pragma unroll
    for (int e = 1; e < NEXP; e++) {
      if (acc[e] > v0) { v0 = acc[e]; b0 = e; }
    }
    int b1 = -1;
    float v1 = -INFINITY;
#pragma unroll
    for (int e = 0; e < NEXP; e++) {
      if (e == b0) continue;
      if (acc[e] > v1) { v1 = acc[e]; b1 = e; }
    }
    float e2 = expf(v1 - v0);
    float p0 = 1.0f / (1.0f + e2);
    float p1 = e2 / (1.0f + e2);
    expert_slot[n] = b0;
    expert_slot[N + n] = b1;
    prob_slot[n] = p0;
    prob_slot[N + n] = p1;
  }
}

// K2: one wave per 64-slot chunk; counts[chunk*NEXP + w] = #matches.
__global__ __launch_bounds__(256) void count_kernel(
    const int* __restrict__ expert_slot, int* __restrict__ counts, int S) {
  const int gid = blockIdx.x * 256 + threadIdx.x;
  const int wave = gid >> 6;  // chunk id
  const int lane = gid & 63;
  const int s = wave * 64 + lane;
  if (s >= S) return;
  const int e = expert_slot[s];
#pragma unroll
  for (int w = 0; w < NEXP; w++) {
    unsigned long long m = __ballot(e == w);
    if (lane == w) counts[wave * NEXP + w] = __popcll(m);
  }
}

// K3: 8 waves; wave w scans 128 chunk counts of expert w (two 64-lane rounds).
// Writes exclusive base[chunk*NEXP+w] and used_cap[w] = min(total, C).
__global__ __launch_bounds__(512) void scan_kernel(
    const int* __restrict__ counts, int* __restrict__ base,
    float* __restrict__ used_cap, int nchunk, int C) {
  const int w = threadIdx.x >> 6;
  const int lane = threadIdx.x & 63;

  int v0 = (lane < nchunk) ? counts[lane * NEXP + w] : 0;
  int s0 = v0;
  for (int off = 1; off < 64; off <<= 1) {
    int t = __shfl_up(s0, off, 64);
    if (lane >= off) s0 += t;
  }
  int total0 = __shfl(s0, 63, 64);
  if (lane < nchunk) base[lane * NEXP + w] = s0 - v0;

  int i1 = 64 + lane;
  int v1 = (i1 < nchunk) ? counts[i1 * NEXP + w] : 0;
  int s1 = v1;
  for (int off = 1; off < 64; off <<= 1) {
    int t = __shfl_up(s1, off, 64);
    if (lane >= off) s1 += t;
  }
  if (i1 < nchunk) base[i1 * NEXP + w] = total0 + s1 - v1;
  int total = total0 + __shfl(s1, 63, 64);
  if (lane == 0) used_cap[w] = (float)(total < C ? total : C);
}

// K4: one wave per chunk; rank = base[chunk][e] + intra-chunk ballot prefix.
__global__ __launch_bounds__(256) void scatter_kernel(
    const int* __restrict__ expert_slot, const float* __restrict__ prob_slot,
    const int* __restrict__ base, float* __restrict__ cb,
    float* __restrict__ sec, int N, int C) {
  const int gid = blockIdx.x * 256 + threadIdx.x;
  const int wave = gid >> 6;  // chunk id
  const int lane = gid & 63;
  const int s = wave * 64 + lane;
  if (s >= 2 * N) return;
  const int e = expert_slot[s];
  const float p = prob_slot[s];
  const unsigned long long below = (1ull << lane) - 1ull;
  int rank = -1;
#pragma unroll
  for (int w = 0; w < NEXP; w++) {
    unsigned long long m = __ballot(e == w);
    if (e == w) rank = base[wave * NEXP + w] + __popcll(m & below);
  }
  if (rank < C) {
    int n = (s >= N) ? (s - N) : s;
    size_t off = ((size_t)n * NEXP + e) * (size_t)C + (size_t)rank;
    cb[off] = p;
    sec[off] = (p != 0.0f) ? 1.0f : 0.0f;
  }
}

extern "C" void kernel_launch(void* const* d_in, const int* in_sizes, int n_in,
                              void* d_out, int out_size, void* d_ws, size_t ws_size,
                              hipStream_t stream) {
  const float* x = (const float*)d_in[0];
  const float* wg = (const float*)d_in[1];

  const int N = in_sizes[0] / HDIM;  // 4096 tokens
  const int K = 2;
  int capacity = (int)floor((double)K * 2.0 * (double)N / (double)NEXP);
  if (capacity < 4) capacity = 4;

  const int S = 2 * N;
  const int nchunk = (S + 63) / 64;  // 128

  float* out = (float*)d_out;
  float* used_cap = out;
  float* cb = out + NEXP;
  float* sec = cb + (size_t)N * NEXP * (size_t)capacity;

  char* ws = (char*)d_ws;
  int* expert_slot = (int*)ws;                              // S ints
  float* prob_slot = (float*)(ws + 4 * (size_t)S);          // S floats
  int* counts = (int*)(ws + 8 * (size_t)S);                 // nchunk*NEXP
  int* base = (int*)(ws + 8 * (size_t)S + 4 * (size_t)(nchunk * NEXP));

  // Zero the (poisoned) 537 MB output via the fast fill path (~6.1 TB/s).
  hipMemsetAsync(d_out, 0, sizeof(float) * (size_t)out_size, stream);

  logits_topk_kernel<<<(N + 3) / 4, 256, 0, stream>>>(x, wg, expert_slot,
                                                      prob_slot, N);
  count_kernel<<<(S + 255) / 256, 256, 0, stream>>>(expert_slot, counts, S);
  scan_kernel<<<1, 512, 0, stream>>>(counts, base, used_cap, nchunk, capacity);
  scatter_kernel<<<(S + 255) / 256, 256, 0, stream>>>(expert_slot, prob_slot,
                                                      base, cb, sec, N,
                                                      capacity);
}